// Round 8
// baseline (222.513 us; speedup 1.0000x reference)
//
#include <hip/hip_runtime.h>
#include <hip/hip_bf16.h>

#define Bq 2
#define Tq 2048
#define Dq 1024
#define Hq 16
#define HDq 64

typedef __attribute__((ext_vector_type(8))) short short8;
typedef __attribute__((ext_vector_type(4))) float f32x4;

__device__ __forceinline__ unsigned short f2bf(float f) {
  union { float f; unsigned int i; } v; v.f = f;
  unsigned int r = v.i + 0x7fffu + ((v.i >> 16) & 1u);
  return (unsigned short)(r >> 16);
}
// fast half-up rounding (hot loop; consistent P for PV and l)
__device__ __forceinline__ unsigned short f2bf_fast(float f) {
  union { float f; unsigned int i; } v; v.f = f;
  return (unsigned short)((v.i + 0x8000u) >> 16);
}

// convert 8 contiguous fp32 -> short8 of bf16 bits
__device__ __forceinline__ short8 cvt8(const float* __restrict__ g) {
  const float4* gp = (const float4*)g;
  float4 x0 = gp[0], x1 = gp[1];
  short8 v;
  v[0] = (short)f2bf(x0.x); v[1] = (short)f2bf(x0.y);
  v[2] = (short)f2bf(x0.z); v[3] = (short)f2bf(x0.w);
  v[4] = (short)f2bf(x1.x); v[5] = (short)f2bf(x1.y);
  v[6] = (short)f2bf(x1.z); v[7] = (short)f2bf(x1.w);
  return v;
}

// async 16B global -> LDS (lands at wave-uniform base + lane*16)
__device__ __forceinline__ void async_cp16(const void* g, void* l) {
  __builtin_amdgcn_global_load_lds(
      (const __attribute__((address_space(1))) void*)g,
      (__attribute__((address_space(3))) void*)l, 16, 0, 0);
}

// ---------------- bf16 pre-convert: x, w_qkv, w_proj --------------------
constexpr int NXC = (Bq * Tq * Dq) / 8;       // 524288 chunks
constexpr int NW1C = (3 * Dq * Dq) / 8;       // 393216
constexpr int NW2C = (Dq * Dq) / 8;           // 131072

__global__ __launch_bounds__(256)
void cvt_all(const float* __restrict__ x, const float* __restrict__ w1,
             const float* __restrict__ w2, unsigned short* __restrict__ xo,
             unsigned short* __restrict__ w1o, unsigned short* __restrict__ w2o)
{
  int i = blockIdx.x * 256 + threadIdx.x;
  const float* src; unsigned short* dst; int j;
  if (i < NXC)              { src = x;  dst = xo;  j = i; }
  else if (i < NXC + NW1C)  { src = w1; dst = w1o; j = i - NXC; }
  else                      { src = w2; dst = w2o; j = i - NXC - NW1C; }
  *(short8*)&dst[(size_t)j * 8] = cvt8(src + (size_t)j * 8);
}

// ---------------- GEMM: C[M,N] = A[M,K] @ W[N,K]^T + bias ----------------
// m97 structure, BK=64 as two 32-col panels (As[2][128][32]): 32 MFMA :
// 16 ds_read_b128 : 8 async cp16 per K-iter; barrier count halved vs BK=32.
// EPI==0 (BN=128): scatter C bf16: q,k -> [B,H,T,HD]; v -> V^T [B,H,HD,T]
// EPI==1 (BN=64):  C fp32 -> outp.
template<int EPI, int BN_>
__global__ __launch_bounds__(256)
void gemm_bt(const unsigned short* __restrict__ Ab, const unsigned short* __restrict__ Wb,
             const float* __restrict__ bias, float* __restrict__ outp,
             int K, int N,
             unsigned short* __restrict__ qo, unsigned short* __restrict__ ko,
             unsigned short* __restrict__ vo)
{
  constexpr int WN = BN_ / 2;
  constexpr int NJ = WN / 16;          // B-frags / acc cols per wave
  constexpr int NAI = 4;               // A staging issues/thread (1024 granules)
  constexpr int NBI = BN_ / 32;        // B staging issues/thread
  __shared__ unsigned short As[2 * 128 * 32];   // 16 KB: panel, row, col
  __shared__ unsigned short Bs[2 * BN_ * 32];

  const int t = threadIdx.x;
  const int lane = t & 63, w = t >> 6;
  const int m0 = blockIdx.y * 128, n0 = blockIdx.x * BN_;
  const int fr = lane & 15, qd = lane >> 4;
  const int wm = (w >> 1) * 64, wn = (w & 1) * WN;

  f32x4 acc[4][NJ] = {};

  for (int k0 = 0; k0 < K; k0 += 64) {
    __syncthreads();
    #pragma unroll
    for (int j = 0; j < NAI; j++) {          // A: 1024 granules of 16B
      int G = j * 256 + t;
      int panel = G >> 9, rowg = (G >> 2) & 127, colg = G & 3;
      async_cp16(Ab + (size_t)(m0 + rowg) * K + k0 + panel * 32 + colg * 8, &As[G * 8]);
    }
    #pragma unroll
    for (int j = 0; j < NBI; j++) {          // B: BN_*8 granules
      int G = j * 256 + t;
      int panel = G >> 9, rowg = (G >> 2) & (BN_ - 1), colg = G & 3;
      if (BN_ == 64) { panel = G >> 8 >> 1; rowg = (G >> 2) & 63; }  // fold for BN=64
      // recompute generically: granules per panel = BN_*4
      panel = G / (BN_ * 4); rowg = (G / 4) % BN_; colg = G & 3;
      async_cp16(Wb + (size_t)(n0 + rowg) * K + k0 + panel * 32 + colg * 8, &Bs[G * 8]);
    }
    __syncthreads();
    #pragma unroll
    for (int kh = 0; kh < 2; kh++) {
      short8 af[4], bf[NJ];
      #pragma unroll
      for (int ib = 0; ib < 4; ib++)
        af[ib] = *(const short8*)&As[kh * 4096 + (wm + ib * 16 + fr) * 32 + qd * 8];
      #pragma unroll
      for (int jb = 0; jb < NJ; jb++)
        bf[jb] = *(const short8*)&Bs[kh * (BN_ * 32) + (wn + jb * 16 + fr) * 32 + qd * 8];
      #pragma unroll
      for (int ib = 0; ib < 4; ib++)
        #pragma unroll
        for (int jb = 0; jb < NJ; jb++)
          acc[ib][jb] = __builtin_amdgcn_mfma_f32_16x16x32_bf16(af[ib], bf[jb], acc[ib][jb], 0, 0, 0);
    }
  }

  #pragma unroll
  for (int jb = 0; jb < NJ; jb++) {
    int col = n0 + wn + jb * 16 + fr;
    float bv = bias[col];
    if (EPI == 0) {
      int which = col >> 10;       // uniform per block (BN divides 1024)
      int rem = col & 1023;
      int hh = rem >> 6, dd = rem & 63;
      #pragma unroll
      for (int ib = 0; ib < 4; ib++) {
        int row4 = m0 + wm + ib * 16 + qd * 4;
        int bb = row4 >> 11, tt = row4 & (Tq - 1);
        if (which == 2) {
          unsigned lo = (unsigned)f2bf(acc[ib][jb][0] + bv)
                      | ((unsigned)f2bf(acc[ib][jb][1] + bv) << 16);
          unsigned hi = (unsigned)f2bf(acc[ib][jb][2] + bv)
                      | ((unsigned)f2bf(acc[ib][jb][3] + bv) << 16);
          uint2 pk; pk.x = lo; pk.y = hi;
          *(uint2*)&vo[((size_t)(bb * Hq + hh) * HDq + dd) * Tq + tt] = pk;
        } else {
          unsigned short* dst = (which == 0) ? qo : ko;
          #pragma unroll
          for (int r = 0; r < 4; r++)
            dst[((size_t)(bb * Hq + hh) * Tq + tt + r) * HDq + dd] = f2bf(acc[ib][jb][r] + bv);
        }
      }
    } else {
      #pragma unroll
      for (int ib = 0; ib < 4; ib++)
        #pragma unroll
        for (int r = 0; r < 4; r++) {
          int row = m0 + wm + ib * 16 + qd * 4 + r;
          outp[(size_t)row * N + col] = acc[ib][jb][r] + bv;
        }
    }
  }
}

// ---------------- MFMA flash attention: unpaired strips, dbuf staging ------
// One block = one 64-row strip s (keys 0..s*64+63; one diag tile, the last).
// Grid 32x32 = 1024 blocks, long strips (s=31) first; 42 KB LDS -> 3
// blocks/CU, imbalance handled by backfill. Fixed-max softmax; l via
// ones-MFMA from the same bf16 P as PV.
constexpr int AP = 72;  // padded stride for the P round-trip only

template<bool DIAG>
__device__ __forceinline__ void strip_compute(
    const short8 aq0, const short8 aq1,
    const short8 (&bk)[4][2], const short8 (&bv)[4][2], const short8 ones,
    unsigned short* __restrict__ PsRow, int fr, int qd, int qbase,
    f32x4 (&oacc)[4], f32x4& lacc, float SCL)
{
  f32x4 s4[4] = {};
  #pragma unroll
  for (int nb = 0; nb < 4; nb++) {
    s4[nb] = __builtin_amdgcn_mfma_f32_16x16x32_bf16(aq0, bk[nb][0], s4[nb], 0, 0, 0);
    s4[nb] = __builtin_amdgcn_mfma_f32_16x16x32_bf16(aq1, bk[nb][1], s4[nb], 0, 0, 0);
  }
  #pragma unroll
  for (int nb = 0; nb < 4; nb++)
    #pragma unroll
    for (int reg = 0; reg < 4; reg++) {
      float pv = exp2f(s4[nb][reg] * SCL);
      // key-local (nb*16+fr) vs query-local (qbase+reg), qbase = w*16 + qd*4
      if (DIAG && (nb * 16 + fr) > (qbase + reg)) pv = 0.f;
      PsRow[(qd * 4 + reg) * AP + nb * 16 + fr] = f2bf_fast(pv);
    }
  short8 ap0 = *(const short8*)&PsRow[fr * AP + qd * 8];
  short8 ap1 = *(const short8*)&PsRow[fr * AP + 32 + qd * 8];
  lacc = __builtin_amdgcn_mfma_f32_16x16x32_bf16(ap0, ones, lacc, 0, 0, 0);
  lacc = __builtin_amdgcn_mfma_f32_16x16x32_bf16(ap1, ones, lacc, 0, 0, 0);
  #pragma unroll
  for (int db = 0; db < 4; db++) {
    oacc[db] = __builtin_amdgcn_mfma_f32_16x16x32_bf16(ap0, bv[db][0], oacc[db], 0, 0, 0);
    oacc[db] = __builtin_amdgcn_mfma_f32_16x16x32_bf16(ap1, bv[db][1], oacc[db], 0, 0, 0);
  }
}

__global__ __launch_bounds__(256, 3)
void attn_fwd(const unsigned short* __restrict__ qb, const unsigned short* __restrict__ kb,
              const unsigned short* __restrict__ vtb, unsigned short* __restrict__ ab)
{
  __shared__ unsigned short Ks[2][64 * 64];    // 2 x 8 KB, swizzled
  __shared__ unsigned short Vts[2][64 * 64];   // 2 x 8 KB, swizzled (V^T [d][c])
  __shared__ unsigned short Ps[64 * AP];       // 9 KB, wave-private rows

  const int t = threadIdx.x, w = t >> 6, lane = t & 63;
  const int fr = lane & 15, qd = lane >> 4;
  const int s = 31 - (int)blockIdx.x;          // long strips first
  const int bh = blockIdx.y;
  const int q0 = s * 64;
  const int qbase = w * 16 + qd * 4;           // wave's query-row base (strip-local)

  // Q fragments straight from global (once per block)
  const unsigned short* Qg = qb + ((size_t)bh * Tq + q0) * HDq;
  const short8 aq0 = *(const short8*)(Qg + (w * 16 + fr) * 64 + qd * 8);
  const short8 aq1 = *(const short8*)(Qg + (w * 16 + fr) * 64 + 32 + qd * 8);

  const unsigned short* Kbh = kb + (size_t)bh * Tq * HDq;
  const unsigned short* Vbh = vtb + (size_t)bh * HDq * Tq;

  // swizzled frag-read offsets (shorts): granule p' = (c*4+qd) ^ (fr&7)
  const int off0 = ((qd ^ (fr & 7)) * 8);
  const int off1 = off0 ^ 32;

  // staging: 512 granules/tile; wave w issues j=0,1
  const int G0 = 2 * w * 64 + lane, G1 = G0 + 64;
  const int r0 = G0 >> 3, g0 = (G0 & 7) ^ (r0 & 7);
  const int r1 = G1 >> 3, g1 = (G1 & 7) ^ (r1 & 7);

  short8 ones;
  #pragma unroll
  for (int j = 0; j < 8; j++) ones[j] = (short)0x3F80;  // bf16 1.0

  f32x4 oacc[4] = {};
  f32x4 lacc = {};
  const float SCL = 0.125f * 1.44269504088896f;  // /sqrt(64) * log2(e)

  unsigned short* PsRow = &Ps[(w * 16) * AP];

  // prologue: stage kt=0 into buf 0
  async_cp16(Kbh + (size_t)r0 * 64 + g0 * 8, &Ks[0][G0 * 8]);
  async_cp16(Vbh + (size_t)r0 * Tq + g0 * 8, &Vts[0][G0 * 8]);
  async_cp16(Kbh + (size_t)r1 * 64 + g1 * 8, &Ks[0][G1 * 8]);
  async_cp16(Vbh + (size_t)r1 * Tq + g1 * 8, &Vts[0][G1 * 8]);

  for (int kt = 0; kt <= s; kt++) {
    const int cur = kt & 1;
    __syncthreads();   // drains buf[cur] loads (in flight during prior compute)
    if (kt < s) {
      const int nxt = cur ^ 1;
      const size_t kofs = (size_t)(kt + 1) * 64;
      async_cp16(Kbh + (kofs + r0) * 64 + g0 * 8, &Ks[nxt][G0 * 8]);
      async_cp16(Vbh + (size_t)r0 * Tq + kofs + g0 * 8, &Vts[nxt][G0 * 8]);
      async_cp16(Kbh + (kofs + r1) * 64 + g1 * 8, &Ks[nxt][G1 * 8]);
      async_cp16(Vbh + (size_t)r1 * Tq + kofs + g1 * 8, &Vts[nxt][G1 * 8]);
    }

    short8 bk[4][2], bv[4][2];
    #pragma unroll
    for (int nb = 0; nb < 4; nb++) {
      bk[nb][0] = *(const short8*)&Ks[cur][(nb * 16 + fr) * 64 + off0];
      bk[nb][1] = *(const short8*)&Ks[cur][(nb * 16 + fr) * 64 + off1];
      bv[nb][0] = *(const short8*)&Vts[cur][(nb * 16 + fr) * 64 + off0];
      bv[nb][1] = *(const short8*)&Vts[cur][(nb * 16 + fr) * 64 + off1];
    }

    if (kt == s)
      strip_compute<true >(aq0, aq1, bk, bv, ones, PsRow, fr, qd, qbase, oacc, lacc, SCL);
    else
      strip_compute<false>(aq0, aq1, bk, bv, ones, PsRow, fr, qd, qbase, oacc, lacc, SCL);
  }

  // ---- epilogue: normalize by l (row-summed via ones-MFMA), store bf16 ----
  #pragma unroll
  for (int reg = 0; reg < 4; reg++) {
    float linv = 1.0f / lacc[reg];
    size_t rowoff = ((size_t)(bh >> 4) * Tq + q0 + w * 16 + qd * 4 + reg) * Dq
                  + (bh & 15) * HDq;
    #pragma unroll
    for (int db = 0; db < 4; db++)
      ab[rowoff + db * 16 + fr] = f2bf(oacc[db][reg] * linv);
  }
}

extern "C" void kernel_launch(void* const* d_in, const int* in_sizes, int n_in,
                              void* d_out, int out_size, void* d_ws, size_t ws_size,
                              hipStream_t stream) {
  const float* x      = (const float*)d_in[0];
  const float* w_qkv  = (const float*)d_in[1];
  const float* b_qkv  = (const float*)d_in[2];
  const float* w_proj = (const float*)d_in[3];
  const float* b_proj = (const float*)d_in[4];
  float* out = (float*)d_out;

  unsigned short* ws = (unsigned short*)d_ws;
  const size_t NE = (size_t)Bq * Hq * Tq * HDq;   // 4,194,304
  unsigned short* qb  = ws;
  unsigned short* kb  = ws + NE;
  unsigned short* vtb = ws + 2 * NE;   // V^T: [B,H,HD,T]
  unsigned short* ab  = ws + 3 * NE;
  unsigned short* xb  = ws + 4 * NE;             // bf16 x      [4096,1024]
  unsigned short* wqb = xb + (size_t)NXC * 8;    // bf16 w_qkv  [3072,1024]
  unsigned short* wpb = wqb + (size_t)NW1C * 8;  // bf16 w_proj [1024,1024]

  dim3 blk(256);
  cvt_all<<<dim3((NXC + NW1C + NW2C) >> 8), blk, 0, stream>>>(x, w_qkv, w_proj, xb, wqb, wpb);

  dim3 g1(3 * Dq / 128, Bq * Tq / 128);   // 24 x 32
  gemm_bt<0, 128><<<g1, blk, 0, stream>>>(xb, wqb, b_qkv, nullptr,
                                          Dq, 3 * Dq, qb, kb, vtb);
  dim3 g2(32, Bq * Hq);                   // strips: 32 x 32, long first
  attn_fwd<<<g2, blk, 0, stream>>>(qb, kb, vtb, ab);
  dim3 g3(Dq / 64, Bq * Tq / 128);        // 16 x 32
  gemm_bt<1, 64><<<g3, blk, 0, stream>>>(ab, wpb, b_proj, out,
                                         Dq, Dq, nullptr, nullptr, nullptr);
}

// Round 9
// 198.293 us; speedup vs baseline: 1.1221x; 1.1221x over previous
//
#include <hip/hip_runtime.h>
#include <hip/hip_bf16.h>

#define Bq 2
#define Tq 2048
#define Dq 1024
#define Hq 16
#define HDq 64

typedef __attribute__((ext_vector_type(8))) short short8;
typedef __attribute__((ext_vector_type(4))) float f32x4;

__device__ __forceinline__ unsigned short f2bf(float f) {
  union { float f; unsigned int i; } v; v.f = f;
  unsigned int r = v.i + 0x7fffu + ((v.i >> 16) & 1u);
  return (unsigned short)(r >> 16);
}
// fast half-up rounding (hot loop; consistent P for PV and l)
__device__ __forceinline__ unsigned short f2bf_fast(float f) {
  union { float f; unsigned int i; } v; v.f = f;
  return (unsigned short)((v.i + 0x8000u) >> 16);
}

// convert 8 contiguous fp32 -> short8 of bf16 bits
__device__ __forceinline__ short8 cvt8(const float* __restrict__ g) {
  const float4* gp = (const float4*)g;
  float4 x0 = gp[0], x1 = gp[1];
  short8 v;
  v[0] = (short)f2bf(x0.x); v[1] = (short)f2bf(x0.y);
  v[2] = (short)f2bf(x0.z); v[3] = (short)f2bf(x0.w);
  v[4] = (short)f2bf(x1.x); v[5] = (short)f2bf(x1.y);
  v[6] = (short)f2bf(x1.z); v[7] = (short)f2bf(x1.w);
  return v;
}

// async 16B global -> LDS (lands at wave-uniform base + lane*16)
__device__ __forceinline__ void async_cp16(const void* g, void* l) {
  __builtin_amdgcn_global_load_lds(
      (const __attribute__((address_space(1))) void*)g,
      (__attribute__((address_space(3))) void*)l, 16, 0, 0);
}

// ---------------- bf16 pre-convert: x, w_qkv, w_proj --------------------
constexpr int NXC = (Bq * Tq * Dq) / 8;       // 524288 chunks
constexpr int NW1C = (3 * Dq * Dq) / 8;       // 393216
constexpr int NW2C = (Dq * Dq) / 8;           // 131072

__global__ __launch_bounds__(256)
void cvt_all(const float* __restrict__ x, const float* __restrict__ w1,
             const float* __restrict__ w2, unsigned short* __restrict__ xo,
             unsigned short* __restrict__ w1o, unsigned short* __restrict__ w2o)
{
  int i = blockIdx.x * 256 + threadIdx.x;
  const float* src; unsigned short* dst; int j;
  if (i < NXC)              { src = x;  dst = xo;  j = i; }
  else if (i < NXC + NW1C)  { src = w1; dst = w1o; j = i - NXC; }
  else                      { src = w2; dst = w2o; j = i - NXC - NW1C; }
  *(short8*)&dst[(size_t)j * 8] = cvt8(src + (size_t)j * 8);
}

// ---------------- GEMM: C[M,N] = A[M,K] @ W[N,K]^T + bias ----------------
// m97 frag/staging layout, BK=64 (two 32-col panels), DOUBLE-BUFFERED:
// issue chunk i+1's global_load_lds right after the barrier, compute chunk i
// -> the vmcnt drain overlaps a full compute phase (matters at K=1024).
// EPI==0 (BN=128): scatter C bf16: q,k -> [B,H,T,HD]; v -> V^T [B,H,HD,T]
// EPI==1 (BN=64):  C fp32 -> outp.
template<int EPI, int BN_>
__global__ __launch_bounds__(256)
void gemm_bt(const unsigned short* __restrict__ Ab, const unsigned short* __restrict__ Wb,
             const float* __restrict__ bias, float* __restrict__ outp,
             int K, int N,
             unsigned short* __restrict__ qo, unsigned short* __restrict__ ko,
             unsigned short* __restrict__ vo)
{
  constexpr int WN = BN_ / 2;
  constexpr int NJ = WN / 16;          // B-frags / acc cols per wave
  constexpr int NAI = 4;               // A staging issues/thread (1024 granules)
  constexpr int NBI = BN_ / 32;        // B staging issues/thread
  __shared__ unsigned short As[2][2 * 128 * 32];   // [buf][panel|row|col] 32 KB
  __shared__ unsigned short Bs[2][2 * BN_ * 32];

  const int t = threadIdx.x;
  const int lane = t & 63, w = t >> 6;
  const int m0 = blockIdx.y * 128, n0 = blockIdx.x * BN_;
  const int fr = lane & 15, qd = lane >> 4;
  const int wm = (w >> 1) * 64, wn = (w & 1) * WN;

  f32x4 acc[4][NJ] = {};
  const int NIT = K / 64;

  // prologue: stage chunk 0 into buf 0
  #pragma unroll
  for (int j = 0; j < NAI; j++) {
    int G = j * 256 + t;
    int panel = G >> 9, rowg = (G >> 2) & 127, colg = G & 3;
    async_cp16(Ab + (size_t)(m0 + rowg) * K + panel * 32 + colg * 8, &As[0][G * 8]);
  }
  #pragma unroll
  for (int j = 0; j < NBI; j++) {
    int G = j * 256 + t;
    int panel = G / (BN_ * 4), rowg = (G / 4) % BN_, colg = G & 3;
    async_cp16(Wb + (size_t)(n0 + rowg) * K + panel * 32 + colg * 8, &Bs[0][G * 8]);
  }

  for (int i = 0; i < NIT; i++) {
    const int cur = i & 1;
    __syncthreads();                       // drains buf[cur] (in flight 1 iter)
    if (i + 1 < NIT) {
      const int nxt = cur ^ 1;
      const int k0 = (i + 1) * 64;
      #pragma unroll
      for (int j = 0; j < NAI; j++) {
        int G = j * 256 + t;
        int panel = G >> 9, rowg = (G >> 2) & 127, colg = G & 3;
        async_cp16(Ab + (size_t)(m0 + rowg) * K + k0 + panel * 32 + colg * 8, &As[nxt][G * 8]);
      }
      #pragma unroll
      for (int j = 0; j < NBI; j++) {
        int G = j * 256 + t;
        int panel = G / (BN_ * 4), rowg = (G / 4) % BN_, colg = G & 3;
        async_cp16(Wb + (size_t)(n0 + rowg) * K + k0 + panel * 32 + colg * 8, &Bs[nxt][G * 8]);
      }
    }
    #pragma unroll
    for (int kh = 0; kh < 2; kh++) {
      short8 af[4], bf[NJ];
      #pragma unroll
      for (int ib = 0; ib < 4; ib++)
        af[ib] = *(const short8*)&As[cur][kh * 4096 + (wm + ib * 16 + fr) * 32 + qd * 8];
      #pragma unroll
      for (int jb = 0; jb < NJ; jb++)
        bf[jb] = *(const short8*)&Bs[cur][kh * (BN_ * 32) + (wn + jb * 16 + fr) * 32 + qd * 8];
      #pragma unroll
      for (int ib = 0; ib < 4; ib++)
        #pragma unroll
        for (int jb = 0; jb < NJ; jb++)
          acc[ib][jb] = __builtin_amdgcn_mfma_f32_16x16x32_bf16(af[ib], bf[jb], acc[ib][jb], 0, 0, 0);
    }
  }

  #pragma unroll
  for (int jb = 0; jb < NJ; jb++) {
    int col = n0 + wn + jb * 16 + fr;
    float bv = bias[col];
    if (EPI == 0) {
      int which = col >> 10;       // uniform per block (BN divides 1024)
      int rem = col & 1023;
      int hh = rem >> 6, dd = rem & 63;
      #pragma unroll
      for (int ib = 0; ib < 4; ib++) {
        int row4 = m0 + wm + ib * 16 + qd * 4;
        int bb = row4 >> 11, tt = row4 & (Tq - 1);
        if (which == 2) {
          unsigned lo = (unsigned)f2bf(acc[ib][jb][0] + bv)
                      | ((unsigned)f2bf(acc[ib][jb][1] + bv) << 16);
          unsigned hi = (unsigned)f2bf(acc[ib][jb][2] + bv)
                      | ((unsigned)f2bf(acc[ib][jb][3] + bv) << 16);
          uint2 pk; pk.x = lo; pk.y = hi;
          *(uint2*)&vo[((size_t)(bb * Hq + hh) * HDq + dd) * Tq + tt] = pk;
        } else {
          unsigned short* dst = (which == 0) ? qo : ko;
          #pragma unroll
          for (int r = 0; r < 4; r++)
            dst[((size_t)(bb * Hq + hh) * Tq + tt + r) * HDq + dd] = f2bf(acc[ib][jb][r] + bv);
        }
      }
    } else {
      #pragma unroll
      for (int ib = 0; ib < 4; ib++)
        #pragma unroll
        for (int r = 0; r < 4; r++) {
          int row = m0 + wm + ib * 16 + qd * 4 + r;
          outp[(size_t)row * N + col] = acc[ib][jb][r] + bv;
        }
    }
  }
}

// ---------------- MFMA flash attention: strip-paired + interleaved ----------
// Round-7 structure (paired strips p / 31-p, 33 strip-iters per block —
// perfect balance, fewest barriers) with the two strips' latency chains
// INTERLEAVED when both are active: S-MFMAs both, exp/P-write both, ap reads
// both, PV both -> 2x ILP on the MFMA->exp->ds_write->ds_read->MFMA chain.
// Big diag (kt=31-p>=16) and small diag (kt=p<=15) are disjoint.
constexpr int AP = 72;  // padded stride for the P round-trip only

template<bool DIAG>
__device__ __forceinline__ void strip_one(
    const short8 aq0, const short8 aq1,
    const short8 (&bk)[4][2], const short8 (&bv)[4][2], const short8 ones,
    unsigned short* __restrict__ PsRow, int fr, int qd, int qbase,
    f32x4 (&oacc)[4], f32x4& lacc, float SCL)
{
  f32x4 s4[4] = {};
  #pragma unroll
  for (int nb = 0; nb < 4; nb++) {
    s4[nb] = __builtin_amdgcn_mfma_f32_16x16x32_bf16(aq0, bk[nb][0], s4[nb], 0, 0, 0);
    s4[nb] = __builtin_amdgcn_mfma_f32_16x16x32_bf16(aq1, bk[nb][1], s4[nb], 0, 0, 0);
  }
  #pragma unroll
  for (int nb = 0; nb < 4; nb++)
    #pragma unroll
    for (int reg = 0; reg < 4; reg++) {
      float pv = exp2f(s4[nb][reg] * SCL);
      if (DIAG && (nb * 16 + fr) > (qbase + reg)) pv = 0.f;
      PsRow[(qd * 4 + reg) * AP + nb * 16 + fr] = f2bf_fast(pv);
    }
  short8 ap0 = *(const short8*)&PsRow[fr * AP + qd * 8];
  short8 ap1 = *(const short8*)&PsRow[fr * AP + 32 + qd * 8];
  lacc = __builtin_amdgcn_mfma_f32_16x16x32_bf16(ap0, ones, lacc, 0, 0, 0);
  lacc = __builtin_amdgcn_mfma_f32_16x16x32_bf16(ap1, ones, lacc, 0, 0, 0);
  #pragma unroll
  for (int db = 0; db < 4; db++) {
    oacc[db] = __builtin_amdgcn_mfma_f32_16x16x32_bf16(ap0, bv[db][0], oacc[db], 0, 0, 0);
    oacc[db] = __builtin_amdgcn_mfma_f32_16x16x32_bf16(ap1, bv[db][1], oacc[db], 0, 0, 0);
  }
}

template<bool SMALLDIAG>
__device__ __forceinline__ void strip_dual(
    const short8 (&aqB)[2], const short8 (&aqA)[2],
    const short8 (&bk)[4][2], const short8 (&bv)[4][2], const short8 ones,
    unsigned short* __restrict__ PsB, unsigned short* __restrict__ PsA,
    int fr, int qd, int qbase,
    f32x4 (&oB)[4], f32x4& lB, f32x4 (&oA)[4], f32x4& lA, float SCL)
{
  f32x4 sB[4] = {}, sA[4] = {};
  #pragma unroll
  for (int nb = 0; nb < 4; nb++) {
    sB[nb] = __builtin_amdgcn_mfma_f32_16x16x32_bf16(aqB[0], bk[nb][0], sB[nb], 0, 0, 0);
    sA[nb] = __builtin_amdgcn_mfma_f32_16x16x32_bf16(aqA[0], bk[nb][0], sA[nb], 0, 0, 0);
  }
  #pragma unroll
  for (int nb = 0; nb < 4; nb++) {
    sB[nb] = __builtin_amdgcn_mfma_f32_16x16x32_bf16(aqB[1], bk[nb][1], sB[nb], 0, 0, 0);
    sA[nb] = __builtin_amdgcn_mfma_f32_16x16x32_bf16(aqA[1], bk[nb][1], sA[nb], 0, 0, 0);
  }
  #pragma unroll
  for (int nb = 0; nb < 4; nb++)
    #pragma unroll
    for (int reg = 0; reg < 4; reg++) {
      float pvB = exp2f(sB[nb][reg] * SCL);
      float pvA = exp2f(sA[nb][reg] * SCL);
      if (SMALLDIAG && (nb * 16 + fr) > (qbase + reg)) pvA = 0.f;
      PsB[(qd * 4 + reg) * AP + nb * 16 + fr] = f2bf_fast(pvB);
      PsA[(qd * 4 + reg) * AP + nb * 16 + fr] = f2bf_fast(pvA);
    }
  short8 apB0 = *(const short8*)&PsB[fr * AP + qd * 8];
  short8 apB1 = *(const short8*)&PsB[fr * AP + 32 + qd * 8];
  short8 apA0 = *(const short8*)&PsA[fr * AP + qd * 8];
  short8 apA1 = *(const short8*)&PsA[fr * AP + 32 + qd * 8];
  lB = __builtin_amdgcn_mfma_f32_16x16x32_bf16(apB0, ones, lB, 0, 0, 0);
  lA = __builtin_amdgcn_mfma_f32_16x16x32_bf16(apA0, ones, lA, 0, 0, 0);
  lB = __builtin_amdgcn_mfma_f32_16x16x32_bf16(apB1, ones, lB, 0, 0, 0);
  lA = __builtin_amdgcn_mfma_f32_16x16x32_bf16(apA1, ones, lA, 0, 0, 0);
  #pragma unroll
  for (int db = 0; db < 4; db++) {
    oB[db] = __builtin_amdgcn_mfma_f32_16x16x32_bf16(apB0, bv[db][0], oB[db], 0, 0, 0);
    oA[db] = __builtin_amdgcn_mfma_f32_16x16x32_bf16(apA0, bv[db][0], oA[db], 0, 0, 0);
  }
  #pragma unroll
  for (int db = 0; db < 4; db++) {
    oB[db] = __builtin_amdgcn_mfma_f32_16x16x32_bf16(apB1, bv[db][1], oB[db], 0, 0, 0);
    oA[db] = __builtin_amdgcn_mfma_f32_16x16x32_bf16(apA1, bv[db][1], oA[db], 0, 0, 0);
  }
}

__global__ __launch_bounds__(256, 2)
void attn_fwd(const unsigned short* __restrict__ qb, const unsigned short* __restrict__ kb,
              const unsigned short* __restrict__ vtb, unsigned short* __restrict__ ab)
{
  __shared__ unsigned short Ks[2][64 * 64];    // 2 x 8 KB, swizzled
  __shared__ unsigned short Vts[2][64 * 64];   // 2 x 8 KB, swizzled (V^T [d][c])
  __shared__ unsigned short Ps[128 * AP];      // 18 KB, wave-private rows

  const int t = threadIdx.x, w = t >> 6, lane = t & 63;
  const int fr = lane & 15, qd = lane >> 4;
  const int p = blockIdx.x;                    // 0..15
  const int bh = blockIdx.y;
  const int sB = 31 - p;                       // big strip (tl=0)
  const int sA = p;                            // small strip (tl=1)
  const int s0t[2] = { sB * 64, sA * 64 };     // strip row bases
  const int ktB = sB;                          // loop end == big strip's diag
  const int qbase = w * 16 + qd * 4;           // wave's query-row base (strip-local)

  // Q fragments straight from global (once per block): [tile][half]
  short8 aq[2][2];
  #pragma unroll
  for (int tl = 0; tl < 2; tl++) {
    const unsigned short* Qg = qb + ((size_t)bh * Tq + s0t[tl]) * HDq;
    #pragma unroll
    for (int c = 0; c < 2; c++)
      aq[tl][c] = *(const short8*)(Qg + (w * 16 + fr) * 64 + c * 32 + qd * 8);
  }

  const unsigned short* Kbh = kb + (size_t)bh * Tq * HDq;
  const unsigned short* Vbh = vtb + (size_t)bh * HDq * Tq;

  // swizzled frag-read offsets (shorts): granule p' = (c*4+qd) ^ (fr&7)
  const int off0 = ((qd ^ (fr & 7)) * 8);
  const int off1 = off0 ^ 32;

  // staging: 8 granules/tile; wave w issues j=0,1
  const int G0 = 2 * w * 64 + lane, G1 = G0 + 64;
  const int r0 = G0 >> 3, g0 = (G0 & 7) ^ (r0 & 7);
  const int r1 = G1 >> 3, g1 = (G1 & 7) ^ (r1 & 7);

  short8 ones;
  #pragma unroll
  for (int j = 0; j < 8; j++) ones[j] = (short)0x3F80;  // bf16 1.0

  f32x4 oacc[2][4] = {};
  f32x4 lacc[2] = {};
  const float SCL = 0.125f * 1.44269504088896f;  // /sqrt(64) * log2(e)

  unsigned short* PsB = &Ps[(0 * 64 + w * 16) * AP];
  unsigned short* PsA = &Ps[(1 * 64 + w * 16) * AP];

  // prologue: stage kt=0 into buf 0
  async_cp16(Kbh + (size_t)r0 * 64 + g0 * 8, &Ks[0][G0 * 8]);
  async_cp16(Vbh + (size_t)r0 * Tq + g0 * 8, &Vts[0][G0 * 8]);
  async_cp16(Kbh + (size_t)r1 * 64 + g1 * 8, &Ks[0][G1 * 8]);
  async_cp16(Vbh + (size_t)r1 * Tq + g1 * 8, &Vts[0][G1 * 8]);

  for (int kt = 0; kt <= ktB; kt++) {
    const int cur = kt & 1;
    __syncthreads();   // drains buf[cur] loads (in flight during prior compute)
    if (kt < ktB) {
      const int nxt = cur ^ 1;
      const size_t kofs = (size_t)(kt + 1) * 64;
      async_cp16(Kbh + (kofs + r0) * 64 + g0 * 8, &Ks[nxt][G0 * 8]);
      async_cp16(Vbh + (size_t)r0 * Tq + kofs + g0 * 8, &Vts[nxt][G0 * 8]);
      async_cp16(Kbh + (kofs + r1) * 64 + g1 * 8, &Ks[nxt][G1 * 8]);
      async_cp16(Vbh + (size_t)r1 * Tq + kofs + g1 * 8, &Vts[nxt][G1 * 8]);
    }

    // ---- K / V fragments (shared by both strips) ----
    short8 bk[4][2], bv[4][2];
    #pragma unroll
    for (int nb = 0; nb < 4; nb++) {
      bk[nb][0] = *(const short8*)&Ks[cur][(nb * 16 + fr) * 64 + off0];
      bk[nb][1] = *(const short8*)&Ks[cur][(nb * 16 + fr) * 64 + off1];
      bv[nb][0] = *(const short8*)&Vts[cur][(nb * 16 + fr) * 64 + off0];
      bv[nb][1] = *(const short8*)&Vts[cur][(nb * 16 + fr) * 64 + off1];
    }

    if (kt < sA) {          // both strips, no diag: interleaved
      strip_dual<false>(aq[0], aq[1], bk, bv, ones, PsB, PsA, fr, qd, qbase,
                        oacc[0], lacc[0], oacc[1], lacc[1], SCL);
    } else if (kt == sA) {  // both strips, small diag: interleaved
      strip_dual<true >(aq[0], aq[1], bk, bv, ones, PsB, PsA, fr, qd, qbase,
                        oacc[0], lacc[0], oacc[1], lacc[1], SCL);
    } else if (kt == ktB) { // big strip only, diag (last iter)
      strip_one<true >(aq[0][0], aq[0][1], bk, bv, ones, PsB, fr, qd, qbase,
                       oacc[0], lacc[0], SCL);
    } else {                // big strip only
      strip_one<false>(aq[0][0], aq[0][1], bk, bv, ones, PsB, fr, qd, qbase,
                       oacc[0], lacc[0], SCL);
    }
  }

  // ---- epilogue: normalize by l (row-summed via ones-MFMA), store bf16 ----
  #pragma unroll
  for (int tl = 0; tl < 2; tl++)
    #pragma unroll
    for (int reg = 0; reg < 4; reg++) {
      float linv = 1.0f / lacc[tl][reg];
      size_t rowoff = ((size_t)(bh >> 4) * Tq + s0t[tl] + w * 16 + qd * 4 + reg) * Dq
                    + (bh & 15) * HDq;
      #pragma unroll
      for (int db = 0; db < 4; db++)
        ab[rowoff + db * 16 + fr] = f2bf(oacc[tl][db][reg] * linv);
    }
}

extern "C" void kernel_launch(void* const* d_in, const int* in_sizes, int n_in,
                              void* d_out, int out_size, void* d_ws, size_t ws_size,
                              hipStream_t stream) {
  const float* x      = (const float*)d_in[0];
  const float* w_qkv  = (const float*)d_in[1];
  const float* b_qkv  = (const float*)d_in[2];
  const float* w_proj = (const float*)d_in[3];
  const float* b_proj = (const float*)d_in[4];
  float* out = (float*)d_out;

  unsigned short* ws = (unsigned short*)d_ws;
  const size_t NE = (size_t)Bq * Hq * Tq * HDq;   // 4,194,304
  unsigned short* qb  = ws;
  unsigned short* kb  = ws + NE;
  unsigned short* vtb = ws + 2 * NE;   // V^T: [B,H,HD,T]
  unsigned short* ab  = ws + 3 * NE;
  unsigned short* xb  = ws + 4 * NE;             // bf16 x      [4096,1024]
  unsigned short* wqb = xb + (size_t)NXC * 8;    // bf16 w_qkv  [3072,1024]
  unsigned short* wpb = wqb + (size_t)NW1C * 8;  // bf16 w_proj [1024,1024]

  dim3 blk(256);
  cvt_all<<<dim3((NXC + NW1C + NW2C) >> 8), blk, 0, stream>>>(x, w_qkv, w_proj, xb, wqb, wpb);

  dim3 g1(3 * Dq / 128, Bq * Tq / 128);   // 24 x 32
  gemm_bt<0, 128><<<g1, blk, 0, stream>>>(xb, wqb, b_qkv, nullptr,
                                          Dq, 3 * Dq, qb, kb, vtb);
  dim3 g2(16, Bq * Hq);                   // strip pairs: 16 x 32
  attn_fwd<<<g2, blk, 0, stream>>>(qb, kb, vtb, ab);
  dim3 g3(Dq / 64, Bq * Tq / 128);        // 16 x 32
  gemm_bt<1, 64><<<g3, blk, 0, stream>>>(ab, wpb, b_proj, out,
                                         Dq, Dq, nullptr, nullptr, nullptr);
}

// Round 10
// 188.889 us; speedup vs baseline: 1.1780x; 1.0498x over previous
//
#include <hip/hip_runtime.h>
#include <hip/hip_bf16.h>

#define Bq 2
#define Tq 2048
#define Dq 1024
#define Hq 16
#define HDq 64

typedef __attribute__((ext_vector_type(8))) short short8;
typedef __attribute__((ext_vector_type(4))) float f32x4;

__device__ __forceinline__ unsigned short f2bf(float f) {
  union { float f; unsigned int i; } v; v.f = f;
  unsigned int r = v.i + 0x7fffu + ((v.i >> 16) & 1u);
  return (unsigned short)(r >> 16);
}
// fast half-up rounding (hot loop; consistent P for PV and l)
__device__ __forceinline__ unsigned short f2bf_fast(float f) {
  union { float f; unsigned int i; } v; v.f = f;
  return (unsigned short)((v.i + 0x8000u) >> 16);
}

// convert 8 contiguous fp32 -> short8 of bf16 bits
__device__ __forceinline__ short8 cvt8(const float* __restrict__ g) {
  const float4* gp = (const float4*)g;
  float4 x0 = gp[0], x1 = gp[1];
  short8 v;
  v[0] = (short)f2bf(x0.x); v[1] = (short)f2bf(x0.y);
  v[2] = (short)f2bf(x0.z); v[3] = (short)f2bf(x0.w);
  v[4] = (short)f2bf(x1.x); v[5] = (short)f2bf(x1.y);
  v[6] = (short)f2bf(x1.z); v[7] = (short)f2bf(x1.w);
  return v;
}

// async 16B global -> LDS (lands at wave-uniform base + lane*16)
__device__ __forceinline__ void async_cp16(const void* g, void* l) {
  __builtin_amdgcn_global_load_lds(
      (const __attribute__((address_space(1))) void*)g,
      (__attribute__((address_space(3))) void*)l, 16, 0, 0);
}

// ---------------- bf16 pre-convert: x, w_qkv, w_proj --------------------
constexpr int NXC = (Bq * Tq * Dq) / 8;       // 524288 chunks
constexpr int NW1C = (3 * Dq * Dq) / 8;       // 393216
constexpr int NW2C = (Dq * Dq) / 8;           // 131072

__global__ __launch_bounds__(256)
void cvt_all(const float* __restrict__ x, const float* __restrict__ w1,
             const float* __restrict__ w2, unsigned short* __restrict__ xo,
             unsigned short* __restrict__ w1o, unsigned short* __restrict__ w2o)
{
  int i = blockIdx.x * 256 + threadIdx.x;
  const float* src; unsigned short* dst; int j;
  if (i < NXC)              { src = x;  dst = xo;  j = i; }
  else if (i < NXC + NW1C)  { src = w1; dst = w1o; j = i - NXC; }
  else                      { src = w2; dst = w2o; j = i - NXC - NW1C; }
  *(short8*)&dst[(size_t)j * 8] = cvt8(src + (size_t)j * 8);
}

// ---------------- GEMM: C[M,N] = A[M,K] @ W[N,K]^T + bias ----------------
// m97 structure, BK=64 as two 32-col panels, SINGLE-buffered (R8 config:
// dbuf at these sizes costs 64 KB LDS -> m132 occupancy cliff, measured -6us).
// Template over BM_: gemm1 128x128 (NI=4), proj 64x128 (NI=2, 24 KB LDS,
// 2 blocks/CU, double the MFMA-per-staged-B-byte of the old BN=64 config).
// EPI==0: scatter C bf16: q,k -> [B,H,T,HD]; v -> V^T [B,H,HD,T]
// EPI==1: C fp32 -> outp.
template<int EPI, int BM_, int BN_>
__global__ __launch_bounds__(256)
void gemm_bt(const unsigned short* __restrict__ Ab, const unsigned short* __restrict__ Wb,
             const float* __restrict__ bias, float* __restrict__ outp,
             int K, int N,
             unsigned short* __restrict__ qo, unsigned short* __restrict__ ko,
             unsigned short* __restrict__ vo)
{
  constexpr int WM = BM_ / 2, WN = BN_ / 2;
  constexpr int NI = WM / 16;          // A-frags / acc rows per wave
  constexpr int NJ = WN / 16;          // B-frags / acc cols per wave
  constexpr int NAI = BM_ / 32;        // A staging issues/thread
  constexpr int NBI = BN_ / 32;        // B staging issues/thread
  __shared__ unsigned short As[2 * BM_ * 32];   // [panel][row][col]
  __shared__ unsigned short Bs[2 * BN_ * 32];

  const int t = threadIdx.x;
  const int lane = t & 63, w = t >> 6;
  const int m0 = blockIdx.y * BM_, n0 = blockIdx.x * BN_;
  const int fr = lane & 15, qd = lane >> 4;
  const int wm = (w >> 1) * WM, wn = (w & 1) * WN;

  f32x4 acc[NI][NJ] = {};

  for (int k0 = 0; k0 < K; k0 += 64) {
    __syncthreads();
    #pragma unroll
    for (int j = 0; j < NAI; j++) {          // A: BM_*8 granules of 16B
      int G = j * 256 + t;
      int panel = G / (BM_ * 4), rowg = (G / 4) % BM_, colg = G & 3;
      async_cp16(Ab + (size_t)(m0 + rowg) * K + k0 + panel * 32 + colg * 8, &As[G * 8]);
    }
    #pragma unroll
    for (int j = 0; j < NBI; j++) {          // B: BN_*8 granules
      int G = j * 256 + t;
      int panel = G / (BN_ * 4), rowg = (G / 4) % BN_, colg = G & 3;
      async_cp16(Wb + (size_t)(n0 + rowg) * K + k0 + panel * 32 + colg * 8, &Bs[G * 8]);
    }
    __syncthreads();
    #pragma unroll
    for (int kh = 0; kh < 2; kh++) {
      short8 af[NI], bf[NJ];
      #pragma unroll
      for (int ib = 0; ib < NI; ib++)
        af[ib] = *(const short8*)&As[kh * (BM_ * 32) + (wm + ib * 16 + fr) * 32 + qd * 8];
      #pragma unroll
      for (int jb = 0; jb < NJ; jb++)
        bf[jb] = *(const short8*)&Bs[kh * (BN_ * 32) + (wn + jb * 16 + fr) * 32 + qd * 8];
      #pragma unroll
      for (int ib = 0; ib < NI; ib++)
        #pragma unroll
        for (int jb = 0; jb < NJ; jb++)
          acc[ib][jb] = __builtin_amdgcn_mfma_f32_16x16x32_bf16(af[ib], bf[jb], acc[ib][jb], 0, 0, 0);
    }
  }

  #pragma unroll
  for (int jb = 0; jb < NJ; jb++) {
    int col = n0 + wn + jb * 16 + fr;
    float bv = bias[col];
    if (EPI == 0) {
      int which = col >> 10;       // uniform per block (BN divides 1024)
      int rem = col & 1023;
      int hh = rem >> 6, dd = rem & 63;
      #pragma unroll
      for (int ib = 0; ib < NI; ib++) {
        int row4 = m0 + wm + ib * 16 + qd * 4;
        int bb = row4 >> 11, tt = row4 & (Tq - 1);
        if (which == 2) {
          unsigned lo = (unsigned)f2bf(acc[ib][jb][0] + bv)
                      | ((unsigned)f2bf(acc[ib][jb][1] + bv) << 16);
          unsigned hi = (unsigned)f2bf(acc[ib][jb][2] + bv)
                      | ((unsigned)f2bf(acc[ib][jb][3] + bv) << 16);
          uint2 pk; pk.x = lo; pk.y = hi;
          *(uint2*)&vo[((size_t)(bb * Hq + hh) * HDq + dd) * Tq + tt] = pk;
        } else {
          unsigned short* dst = (which == 0) ? qo : ko;
          #pragma unroll
          for (int r = 0; r < 4; r++)
            dst[((size_t)(bb * Hq + hh) * Tq + tt + r) * HDq + dd] = f2bf(acc[ib][jb][r] + bv);
        }
      }
    } else {
      #pragma unroll
      for (int ib = 0; ib < NI; ib++)
        #pragma unroll
        for (int r = 0; r < 4; r++) {
          int row = m0 + wm + ib * 16 + qd * 4 + r;
          outp[(size_t)row * N + col] = acc[ib][jb][r] + bv;
        }
    }
  }
}

// ---------------- MFMA flash attention: strip-paired + interleaved ----------
// Paired strips p / 31-p: 33 strip-iters per block (perfect balance, fewest
// barriers); two strips' latency chains interleaved when both active.
// Fixed-max softmax; l via ones-MFMA from the same bf16 P as PV.
constexpr int AP = 72;  // padded stride for the P round-trip only

template<bool DIAG>
__device__ __forceinline__ void strip_one(
    const short8 aq0, const short8 aq1,
    const short8 (&bk)[4][2], const short8 (&bv)[4][2], const short8 ones,
    unsigned short* __restrict__ PsRow, int fr, int qd, int qbase,
    f32x4 (&oacc)[4], f32x4& lacc, float SCL)
{
  f32x4 s4[4] = {};
  #pragma unroll
  for (int nb = 0; nb < 4; nb++) {
    s4[nb] = __builtin_amdgcn_mfma_f32_16x16x32_bf16(aq0, bk[nb][0], s4[nb], 0, 0, 0);
    s4[nb] = __builtin_amdgcn_mfma_f32_16x16x32_bf16(aq1, bk[nb][1], s4[nb], 0, 0, 0);
  }
  #pragma unroll
  for (int nb = 0; nb < 4; nb++)
    #pragma unroll
    for (int reg = 0; reg < 4; reg++) {
      float pv = exp2f(s4[nb][reg] * SCL);
      if (DIAG && (nb * 16 + fr) > (qbase + reg)) pv = 0.f;
      PsRow[(qd * 4 + reg) * AP + nb * 16 + fr] = f2bf_fast(pv);
    }
  short8 ap0 = *(const short8*)&PsRow[fr * AP + qd * 8];
  short8 ap1 = *(const short8*)&PsRow[fr * AP + 32 + qd * 8];
  lacc = __builtin_amdgcn_mfma_f32_16x16x32_bf16(ap0, ones, lacc, 0, 0, 0);
  lacc = __builtin_amdgcn_mfma_f32_16x16x32_bf16(ap1, ones, lacc, 0, 0, 0);
  #pragma unroll
  for (int db = 0; db < 4; db++) {
    oacc[db] = __builtin_amdgcn_mfma_f32_16x16x32_bf16(ap0, bv[db][0], oacc[db], 0, 0, 0);
    oacc[db] = __builtin_amdgcn_mfma_f32_16x16x32_bf16(ap1, bv[db][1], oacc[db], 0, 0, 0);
  }
}

template<bool SMALLDIAG>
__device__ __forceinline__ void strip_dual(
    const short8 (&aqB)[2], const short8 (&aqA)[2],
    const short8 (&bk)[4][2], const short8 (&bv)[4][2], const short8 ones,
    unsigned short* __restrict__ PsB, unsigned short* __restrict__ PsA,
    int fr, int qd, int qbase,
    f32x4 (&oB)[4], f32x4& lB, f32x4 (&oA)[4], f32x4& lA, float SCL)
{
  f32x4 sB[4] = {}, sA[4] = {};
  #pragma unroll
  for (int nb = 0; nb < 4; nb++) {
    sB[nb] = __builtin_amdgcn_mfma_f32_16x16x32_bf16(aqB[0], bk[nb][0], sB[nb], 0, 0, 0);
    sA[nb] = __builtin_amdgcn_mfma_f32_16x16x32_bf16(aqA[0], bk[nb][0], sA[nb], 0, 0, 0);
  }
  #pragma unroll
  for (int nb = 0; nb < 4; nb++) {
    sB[nb] = __builtin_amdgcn_mfma_f32_16x16x32_bf16(aqB[1], bk[nb][1], sB[nb], 0, 0, 0);
    sA[nb] = __builtin_amdgcn_mfma_f32_16x16x32_bf16(aqA[1], bk[nb][1], sA[nb], 0, 0, 0);
  }
  #pragma unroll
  for (int nb = 0; nb < 4; nb++)
    #pragma unroll
    for (int reg = 0; reg < 4; reg++) {
      float pvB = exp2f(sB[nb][reg] * SCL);
      float pvA = exp2f(sA[nb][reg] * SCL);
      if (SMALLDIAG && (nb * 16 + fr) > (qbase + reg)) pvA = 0.f;
      PsB[(qd * 4 + reg) * AP + nb * 16 + fr] = f2bf_fast(pvB);
      PsA[(qd * 4 + reg) * AP + nb * 16 + fr] = f2bf_fast(pvA);
    }
  short8 apB0 = *(const short8*)&PsB[fr * AP + qd * 8];
  short8 apB1 = *(const short8*)&PsB[fr * AP + 32 + qd * 8];
  short8 apA0 = *(const short8*)&PsA[fr * AP + qd * 8];
  short8 apA1 = *(const short8*)&PsA[fr * AP + 32 + qd * 8];
  lB = __builtin_amdgcn_mfma_f32_16x16x32_bf16(apB0, ones, lB, 0, 0, 0);
  lA = __builtin_amdgcn_mfma_f32_16x16x32_bf16(apA0, ones, lA, 0, 0, 0);
  lB = __builtin_amdgcn_mfma_f32_16x16x32_bf16(apB1, ones, lB, 0, 0, 0);
  lA = __builtin_amdgcn_mfma_f32_16x16x32_bf16(apA1, ones, lA, 0, 0, 0);
  #pragma unroll
  for (int db = 0; db < 4; db++) {
    oB[db] = __builtin_amdgcn_mfma_f32_16x16x32_bf16(apB0, bv[db][0], oB[db], 0, 0, 0);
    oA[db] = __builtin_amdgcn_mfma_f32_16x16x32_bf16(apA0, bv[db][0], oA[db], 0, 0, 0);
  }
  #pragma unroll
  for (int db = 0; db < 4; db++) {
    oB[db] = __builtin_amdgcn_mfma_f32_16x16x32_bf16(apB1, bv[db][1], oB[db], 0, 0, 0);
    oA[db] = __builtin_amdgcn_mfma_f32_16x16x32_bf16(apA1, bv[db][1], oA[db], 0, 0, 0);
  }
}

__global__ __launch_bounds__(256, 2)
void attn_fwd(const unsigned short* __restrict__ qb, const unsigned short* __restrict__ kb,
              const unsigned short* __restrict__ vtb, unsigned short* __restrict__ ab)
{
  __shared__ unsigned short Ks[2][64 * 64];    // 2 x 8 KB, swizzled
  __shared__ unsigned short Vts[2][64 * 64];   // 2 x 8 KB, swizzled (V^T [d][c])
  __shared__ unsigned short Ps[128 * AP];      // 18 KB, wave-private rows

  const int t = threadIdx.x, w = t >> 6, lane = t & 63;
  const int fr = lane & 15, qd = lane >> 4;
  const int p = blockIdx.x;                    // 0..15
  const int bh = blockIdx.y;
  const int sB = 31 - p;                       // big strip (tl=0)
  const int sA = p;                            // small strip (tl=1)
  const int s0t[2] = { sB * 64, sA * 64 };     // strip row bases
  const int ktB = sB;                          // loop end == big strip's diag
  const int qbase = w * 16 + qd * 4;           // wave's query-row base (strip-local)

  // Q fragments straight from global (once per block): [tile][half]
  short8 aq[2][2];
  #pragma unroll
  for (int tl = 0; tl < 2; tl++) {
    const unsigned short* Qg = qb + ((size_t)bh * Tq + s0t[tl]) * HDq;
    #pragma unroll
    for (int c = 0; c < 2; c++)
      aq[tl][c] = *(const short8*)(Qg + (w * 16 + fr) * 64 + c * 32 + qd * 8);
  }

  const unsigned short* Kbh = kb + (size_t)bh * Tq * HDq;
  const unsigned short* Vbh = vtb + (size_t)bh * HDq * Tq;

  // swizzled frag-read offsets (shorts): granule p' = (c*4+qd) ^ (fr&7)
  const int off0 = ((qd ^ (fr & 7)) * 8);
  const int off1 = off0 ^ 32;

  // staging: 8 granules/tile; wave w issues j=0,1
  const int G0 = 2 * w * 64 + lane, G1 = G0 + 64;
  const int r0 = G0 >> 3, g0 = (G0 & 7) ^ (r0 & 7);
  const int r1 = G1 >> 3, g1 = (G1 & 7) ^ (r1 & 7);

  short8 ones;
  #pragma unroll
  for (int j = 0; j < 8; j++) ones[j] = (short)0x3F80;  // bf16 1.0

  f32x4 oacc[2][4] = {};
  f32x4 lacc[2] = {};
  const float SCL = 0.125f * 1.44269504088896f;  // /sqrt(64) * log2(e)

  unsigned short* PsB = &Ps[(0 * 64 + w * 16) * AP];
  unsigned short* PsA = &Ps[(1 * 64 + w * 16) * AP];

  // prologue: stage kt=0 into buf 0
  async_cp16(Kbh + (size_t)r0 * 64 + g0 * 8, &Ks[0][G0 * 8]);
  async_cp16(Vbh + (size_t)r0 * Tq + g0 * 8, &Vts[0][G0 * 8]);
  async_cp16(Kbh + (size_t)r1 * 64 + g1 * 8, &Ks[0][G1 * 8]);
  async_cp16(Vbh + (size_t)r1 * Tq + g1 * 8, &Vts[0][G1 * 8]);

  for (int kt = 0; kt <= ktB; kt++) {
    const int cur = kt & 1;
    __syncthreads();   // drains buf[cur] loads (in flight during prior compute)
    if (kt < ktB) {
      const int nxt = cur ^ 1;
      const size_t kofs = (size_t)(kt + 1) * 64;
      async_cp16(Kbh + (kofs + r0) * 64 + g0 * 8, &Ks[nxt][G0 * 8]);
      async_cp16(Vbh + (size_t)r0 * Tq + kofs + g0 * 8, &Vts[nxt][G0 * 8]);
      async_cp16(Kbh + (kofs + r1) * 64 + g1 * 8, &Ks[nxt][G1 * 8]);
      async_cp16(Vbh + (size_t)r1 * Tq + kofs + g1 * 8, &Vts[nxt][G1 * 8]);
    }

    // ---- K / V fragments (shared by both strips) ----
    short8 bk[4][2], bv[4][2];
    #pragma unroll
    for (int nb = 0; nb < 4; nb++) {
      bk[nb][0] = *(const short8*)&Ks[cur][(nb * 16 + fr) * 64 + off0];
      bk[nb][1] = *(const short8*)&Ks[cur][(nb * 16 + fr) * 64 + off1];
      bv[nb][0] = *(const short8*)&Vts[cur][(nb * 16 + fr) * 64 + off0];
      bv[nb][1] = *(const short8*)&Vts[cur][(nb * 16 + fr) * 64 + off1];
    }

    if (kt < sA) {          // both strips, no diag: interleaved
      strip_dual<false>(aq[0], aq[1], bk, bv, ones, PsB, PsA, fr, qd, qbase,
                        oacc[0], lacc[0], oacc[1], lacc[1], SCL);
    } else if (kt == sA) {  // both strips, small diag: interleaved
      strip_dual<true >(aq[0], aq[1], bk, bv, ones, PsB, PsA, fr, qd, qbase,
                        oacc[0], lacc[0], oacc[1], lacc[1], SCL);
    } else if (kt == ktB) { // big strip only, diag (last iter)
      strip_one<true >(aq[0][0], aq[0][1], bk, bv, ones, PsB, fr, qd, qbase,
                       oacc[0], lacc[0], SCL);
    } else {                // big strip only
      strip_one<false>(aq[0][0], aq[0][1], bk, bv, ones, PsB, fr, qd, qbase,
                       oacc[0], lacc[0], SCL);
    }
  }

  // ---- epilogue: normalize by l (row-summed via ones-MFMA), store bf16 ----
  #pragma unroll
  for (int tl = 0; tl < 2; tl++)
    #pragma unroll
    for (int reg = 0; reg < 4; reg++) {
      float linv = 1.0f / lacc[tl][reg];
      size_t rowoff = ((size_t)(bh >> 4) * Tq + s0t[tl] + w * 16 + qd * 4 + reg) * Dq
                    + (bh & 15) * HDq;
      #pragma unroll
      for (int db = 0; db < 4; db++)
        ab[rowoff + db * 16 + fr] = f2bf(oacc[tl][db][reg] * linv);
    }
}

extern "C" void kernel_launch(void* const* d_in, const int* in_sizes, int n_in,
                              void* d_out, int out_size, void* d_ws, size_t ws_size,
                              hipStream_t stream) {
  const float* x      = (const float*)d_in[0];
  const float* w_qkv  = (const float*)d_in[1];
  const float* b_qkv  = (const float*)d_in[2];
  const float* w_proj = (const float*)d_in[3];
  const float* b_proj = (const float*)d_in[4];
  float* out = (float*)d_out;

  unsigned short* ws = (unsigned short*)d_ws;
  const size_t NE = (size_t)Bq * Hq * Tq * HDq;   // 4,194,304
  unsigned short* qb  = ws;
  unsigned short* kb  = ws + NE;
  unsigned short* vtb = ws + 2 * NE;   // V^T: [B,H,HD,T]
  unsigned short* ab  = ws + 3 * NE;
  unsigned short* xb  = ws + 4 * NE;             // bf16 x      [4096,1024]
  unsigned short* wqb = xb + (size_t)NXC * 8;    // bf16 w_qkv  [3072,1024]
  unsigned short* wpb = wqb + (size_t)NW1C * 8;  // bf16 w_proj [1024,1024]

  dim3 blk(256);
  cvt_all<<<dim3((NXC + NW1C + NW2C) >> 8), blk, 0, stream>>>(x, w_qkv, w_proj, xb, wqb, wpb);

  dim3 g1(3 * Dq / 128, Bq * Tq / 128);   // 24 x 32
  gemm_bt<0, 128, 128><<<g1, blk, 0, stream>>>(xb, wqb, b_qkv, nullptr,
                                               Dq, 3 * Dq, qb, kb, vtb);
  dim3 g2(16, Bq * Hq);                   // strip pairs: 16 x 32
  attn_fwd<<<g2, blk, 0, stream>>>(qb, kb, vtb, ab);
  dim3 g3(Dq / 128, Bq * Tq / 64);        // 8 x 64  (proj: 64x128 tiles)
  gemm_bt<1, 64, 128><<<g3, blk, 0, stream>>>(ab, wpb, b_proj, out,
                                              Dq, Dq, nullptr, nullptr, nullptr);
}